// Round 1
// baseline (1562.976 us; speedup 1.0000x reference)
//
#include <hip/hip_runtime.h>
#include <math.h>

#define NB 32
#define NG 500
#define NP 500
#define ND 128
#define NH 8
#define NQK 16
#define NE 8
#define NFF 512
#define NT 16000   // B*G tokens

// ---------------------------------------------------------------------------
// K/V projection: C[16000 x 256] = enc @ [Wk | Wv], written to [B,H,P,16]
// block: 32 rows, 256 threads, thread tile 4 rows x 8 cols
// ---------------------------------------------------------------------------
__global__ __launch_bounds__(256) void k_kv(const float* __restrict__ enc,
                                            const float* __restrict__ Wk,
                                            const float* __restrict__ Wv,
                                            float* __restrict__ kbuf,
                                            float* __restrict__ vbuf) {
  int r0 = blockIdx.x * 32;
  int tid = threadIdx.x;
  __shared__ float encS[32][128];
  const float4* e4 = (const float4*)(enc + (size_t)r0 * 128);
  float4* s4 = (float4*)&encS[0][0];
#pragma unroll
  for (int i = 0; i < 4; i++) s4[tid + i * 256] = e4[tid + i * 256];
  __syncthreads();
  int cg = tid & 31, rg = tid >> 5;
  int c0 = cg * 8;  // col 0..255: [K cols | V cols]
  const float* W0 = (c0 < 128) ? (Wk + c0) : (Wv + (c0 - 128));
  float acc[4][8] = {};
  for (int d = 0; d < 128; d++) {
    float a0 = encS[rg * 4 + 0][d];
    float a1 = encS[rg * 4 + 1][d];
    float a2 = encS[rg * 4 + 2][d];
    float a3 = encS[rg * 4 + 3][d];
    float4 wlo = *(const float4*)(W0 + d * 128);
    float4 whi = *(const float4*)(W0 + d * 128 + 4);
    float w[8] = {wlo.x, wlo.y, wlo.z, wlo.w, whi.x, whi.y, whi.z, whi.w};
#pragma unroll
    for (int j = 0; j < 8; j++) {
      acc[0][j] += a0 * w[j];
      acc[1][j] += a1 * w[j];
      acc[2][j] += a2 * w[j];
      acc[3][j] += a3 * w[j];
    }
  }
#pragma unroll
  for (int i = 0; i < 4; i++) {
    int r = r0 + rg * 4 + i;
    int b = r / 500;
    int p = r - b * 500;
    int cc = (c0 < 128) ? c0 : (c0 - 128);
    int h = cc >> 4, qk = cc & 15;
    float* dst = (c0 < 128 ? kbuf : vbuf) + ((size_t)(b * 8 + h) * 500 + p) * 16 + qk;
    *(float4*)dst = make_float4(acc[i][0], acc[i][1], acc[i][2], acc[i][3]);
    *(float4*)(dst + 4) = make_float4(acc[i][4], acc[i][5], acc[i][6], acc[i][7]);
  }
}

// ---------------------------------------------------------------------------
// graphQ[b][j] = graph[b] @ Wq[0:128, j]
// ---------------------------------------------------------------------------
__global__ void k_graphq(const float* __restrict__ graph,
                         const float* __restrict__ Wq,
                         float* __restrict__ gq) {
  int b = blockIdx.x, j = threadIdx.x;
  float s = 0.f;
  for (int d = 0; d < 128; d++) s += graph[b * 128 + d] * Wq[d * 128 + j];
  gq[b * 128 + j] = s;
}

// ---------------------------------------------------------------------------
// attention: block = (b*8+h, half); 250 queries per block, online softmax
// ---------------------------------------------------------------------------
__global__ __launch_bounds__(256) void k_attn(const float* __restrict__ kbuf,
                                              const float* __restrict__ vbuf,
                                              const float* __restrict__ capacity,
                                              const float* __restrict__ gq,
                                              const float* __restrict__ Wq,
                                              const float* __restrict__ mask,
                                              float* __restrict__ att) {
  int bh = blockIdx.x;           // 0..255
  int half = blockIdx.y;         // 0..1
  int b = bh >> 3, h = bh & 7;
  int tid = threadIdx.x;
  __shared__ float ksh[NP][16];
  __shared__ float vsh[NP][16];
  const float4* kp = (const float4*)(kbuf + (size_t)bh * NP * 16);
  const float4* vp = (const float4*)(vbuf + (size_t)bh * NP * 16);
  float4* k4 = (float4*)&ksh[0][0];
  float4* v4 = (float4*)&vsh[0][0];
  for (int i = tid; i < NP * 4; i += 256) { k4[i] = kp[i]; v4[i] = vp[i]; }
  __syncthreads();
  if (tid < 250) {
    int g = half * 250 + tid;
    float cap = capacity[b * NG + g];
    float q[16];
#pragma unroll
    for (int j = 0; j < 16; j++)
      q[j] = gq[b * 128 + h * 16 + j] + cap * Wq[128 * 128 + h * 16 + j];
    float m = -1e30f, l = 0.f;
    float o[16] = {};
    const float* mrow = mask + ((size_t)(b * NG + g)) * NP;
    for (int p = 0; p < NP; p++) {
      const float4* kr = (const float4*)(&ksh[p][0]);
      float4 ka = kr[0], kb2 = kr[1], kc = kr[2], kd = kr[3];
      float s = q[0] * ka.x + q[1] * ka.y + q[2] * ka.z + q[3] * ka.w
              + q[4] * kb2.x + q[5] * kb2.y + q[6] * kb2.z + q[7] * kb2.w
              + q[8] * kc.x + q[9] * kc.y + q[10] * kc.z + q[11] * kc.w
              + q[12] * kd.x + q[13] * kd.y + q[14] * kd.z + q[15] * kd.w;
      s = s * 0.25f + mrow[p];
      if (s > m) {
        float c = __expf(m - s);
        l *= c;
#pragma unroll
        for (int j = 0; j < 16; j++) o[j] *= c;
        m = s;
      }
      float e = __expf(s - m);
      l += e;
      const float4* vr = (const float4*)(&vsh[p][0]);
      float4 va = vr[0], vb = vr[1], vc = vr[2], vd = vr[3];
      o[0] += e * va.x;  o[1] += e * va.y;  o[2] += e * va.z;  o[3] += e * va.w;
      o[4] += e * vb.x;  o[5] += e * vb.y;  o[6] += e * vb.z;  o[7] += e * vb.w;
      o[8] += e * vc.x;  o[9] += e * vc.y;  o[10] += e * vc.z; o[11] += e * vc.w;
      o[12] += e * vd.x; o[13] += e * vd.y; o[14] += e * vd.z; o[15] += e * vd.w;
    }
    float inv = 1.f / l;
    float* orow = att + ((size_t)(b * NG + g)) * 128 + h * 16;
#pragma unroll
    for (int j = 0; j < 16; j++) orow[j] = o[j] * inv;
  }
}

// ---------------------------------------------------------------------------
// mh = att(16000x128) @ Wcomb(128x128); block 32 rows, thread 2r x 8c
// ---------------------------------------------------------------------------
__global__ __launch_bounds__(256) void k_comb(const float* __restrict__ att,
                                              const float* __restrict__ Wc,
                                              float* __restrict__ mh) {
  int r0 = blockIdx.x * 32;
  int tid = threadIdx.x;
  __shared__ float aS[32][130];
  for (int idx = tid; idx < 32 * 32; idx += 256) {
    int r = idx >> 5, dg = idx & 31;
    float4 v = ((const float4*)att)[(size_t)(r0 + r) * 32 + dg];
    aS[r][dg * 4 + 0] = v.x; aS[r][dg * 4 + 1] = v.y;
    aS[r][dg * 4 + 2] = v.z; aS[r][dg * 4 + 3] = v.w;
  }
  __syncthreads();
  int cg = tid & 15, rg = tid >> 4;
  float acc[2][8] = {};
  for (int d = 0; d < 128; d++) {
    float a0 = aS[rg * 2 + 0][d];
    float a1 = aS[rg * 2 + 1][d];
    float4 wlo = *(const float4*)(Wc + d * 128 + cg * 8);
    float4 whi = *(const float4*)(Wc + d * 128 + cg * 8 + 4);
    float w[8] = {wlo.x, wlo.y, wlo.z, wlo.w, whi.x, whi.y, whi.z, whi.w};
#pragma unroll
    for (int j = 0; j < 8; j++) {
      acc[0][j] += a0 * w[j];
      acc[1][j] += a1 * w[j];
    }
  }
#pragma unroll
  for (int i = 0; i < 2; i++) {
    float* dst = mh + (size_t)(r0 + rg * 2 + i) * 128 + cg * 8;
    *(float4*)dst = make_float4(acc[i][0], acc[i][1], acc[i][2], acc[i][3]);
    *(float4*)(dst + 4) = make_float4(acc[i][4], acc[i][5], acc[i][6], acc[i][7]);
  }
}

// ---------------------------------------------------------------------------
// gating: logits, top-2, softmax gates, expert bucketing + importance
// ---------------------------------------------------------------------------
__global__ __launch_bounds__(256) void k_gate(const float* __restrict__ mh,
                                              const float* __restrict__ wg,
                                              int* __restrict__ tlist,
                                              float* __restrict__ glist,
                                              int* __restrict__ cnt,
                                              float* __restrict__ imp) {
  int t0 = blockIdx.x * 64;
  int tid = threadIdx.x;
  __shared__ float tS[64][129];
  for (int idx = tid; idx < 64 * 32; idx += 256) {
    int r = idx >> 5, dg = idx & 31;
    float4 v = ((const float4*)mh)[(size_t)(t0 + r) * 32 + dg];
    tS[r][dg * 4 + 0] = v.x; tS[r][dg * 4 + 1] = v.y;
    tS[r][dg * 4 + 2] = v.z; tS[r][dg * 4 + 3] = v.w;
  }
  __syncthreads();
  if (tid < 64) {
    float lg[8] = {};
    for (int d = 0; d < 128; d++) {
      float x = tS[tid][d];
#pragma unroll
      for (int k = 0; k < 8; k++) lg[k] += x * wg[d * 8 + k];
    }
    float v0 = -1e30f, v1 = -1e30f;
    int i0 = 0, i1 = 0;
#pragma unroll
    for (int k = 0; k < 8; k++) {
      float l = lg[k];
      if (l > v0) { v1 = v0; i1 = i0; v0 = l; i0 = k; }
      else if (l > v1) { v1 = l; i1 = k; }
    }
    float ex = __expf(v1 - v0);
    float den = 1.0f + ex;
    float g0 = 1.0f / den, g1 = ex / den;
    int t = t0 + tid;
    atomicAdd(&imp[i0], g0);
    atomicAdd(&imp[i1], g1);
    int s0 = atomicAdd(&cnt[i0], 1);
    tlist[i0 * NT + s0] = t; glist[i0 * NT + s0] = g0;
    int s1 = atomicAdd(&cnt[i1], 1);
    tlist[i1 * NT + s1] = t; glist[i1 * NT + s1] = g1;
  }
}

// ---------------------------------------------------------------------------
// MoE expert FFN: block = (token-tile 32, expert); two-stage GEMM via LDS h
// ---------------------------------------------------------------------------
__global__ __launch_bounds__(256) void k_moe(const float* __restrict__ mh,
                                             const float* __restrict__ W1,
                                             const float* __restrict__ b1,
                                             const float* __restrict__ W2,
                                             const float* __restrict__ b2,
                                             const int* __restrict__ tlist,
                                             const float* __restrict__ glist,
                                             const int* __restrict__ cnt,
                                             float* __restrict__ acc) {
  int e = blockIdx.y;
  int n = cnt[e];
  int t0 = blockIdx.x * 32;
  if (t0 >= n) return;
  int tid = threadIdx.x;
  __shared__ float tS[32][129];
  __shared__ float hS[32][65];
  __shared__ int rT[32];
  __shared__ float rG[32];
  if (tid < 32) {
    int ok = (t0 + tid) < n;
    rT[tid] = ok ? tlist[e * NT + t0 + tid] : -1;
    rG[tid] = ok ? glist[e * NT + t0 + tid] : 0.f;
  }
  __syncthreads();
  for (int idx = tid; idx < 32 * 32; idx += 256) {
    int r = idx >> 5, dg = idx & 31;
    int tok = rT[r];
    float4 v = (tok >= 0) ? ((const float4*)mh)[(size_t)tok * 32 + dg]
                          : make_float4(0.f, 0.f, 0.f, 0.f);
    tS[r][dg * 4 + 0] = v.x; tS[r][dg * 4 + 1] = v.y;
    tS[r][dg * 4 + 2] = v.z; tS[r][dg * 4 + 3] = v.w;
  }
  __syncthreads();
  int tc = tid & 15, tr = tid >> 4;
  float y[2][8] = {};
  for (int fc = 0; fc < NFF; fc += 64) {
    // phase A: h chunk [32 tok][64 f], thread = 2 rows x 4 f
    float h00 = 0, h01 = 0, h02 = 0, h03 = 0, h10 = 0, h11 = 0, h12 = 0, h13 = 0;
    const float* w1p = W1 + (size_t)e * ND * NFF + fc + tc * 4;
    for (int d = 0; d < ND; d++) {
      float a0 = tS[tr * 2 + 0][d];
      float a1 = tS[tr * 2 + 1][d];
      float4 w = *(const float4*)(w1p + (size_t)d * NFF);
      h00 += a0 * w.x; h01 += a0 * w.y; h02 += a0 * w.z; h03 += a0 * w.w;
      h10 += a1 * w.x; h11 += a1 * w.y; h12 += a1 * w.z; h13 += a1 * w.w;
    }
    float4 bb = *(const float4*)(b1 + e * NFF + fc + tc * 4);
    hS[tr * 2 + 0][tc * 4 + 0] = fmaxf(h00 + bb.x, 0.f);
    hS[tr * 2 + 0][tc * 4 + 1] = fmaxf(h01 + bb.y, 0.f);
    hS[tr * 2 + 0][tc * 4 + 2] = fmaxf(h02 + bb.z, 0.f);
    hS[tr * 2 + 0][tc * 4 + 3] = fmaxf(h03 + bb.w, 0.f);
    hS[tr * 2 + 1][tc * 4 + 0] = fmaxf(h10 + bb.x, 0.f);
    hS[tr * 2 + 1][tc * 4 + 1] = fmaxf(h11 + bb.y, 0.f);
    hS[tr * 2 + 1][tc * 4 + 2] = fmaxf(h12 + bb.z, 0.f);
    hS[tr * 2 + 1][tc * 4 + 3] = fmaxf(h13 + bb.w, 0.f);
    __syncthreads();
    // phase B: y += relu(h) @ W2chunk, thread = 2 rows x 8 cols
    const float* w2p = W2 + ((size_t)e * NFF + fc) * ND + tc * 8;
    for (int f = 0; f < 64; f++) {
      float p0 = hS[tr * 2 + 0][f];
      float p1 = hS[tr * 2 + 1][f];
      float4 wa = *(const float4*)(w2p + (size_t)f * ND);
      float4 wb = *(const float4*)(w2p + (size_t)f * ND + 4);
      y[0][0] += p0 * wa.x; y[0][1] += p0 * wa.y; y[0][2] += p0 * wa.z; y[0][3] += p0 * wa.w;
      y[0][4] += p0 * wb.x; y[0][5] += p0 * wb.y; y[0][6] += p0 * wb.z; y[0][7] += p0 * wb.w;
      y[1][0] += p1 * wa.x; y[1][1] += p1 * wa.y; y[1][2] += p1 * wa.z; y[1][3] += p1 * wa.w;
      y[1][4] += p1 * wb.x; y[1][5] += p1 * wb.y; y[1][6] += p1 * wb.z; y[1][7] += p1 * wb.w;
    }
    __syncthreads();
  }
#pragma unroll
  for (int i = 0; i < 2; i++) {
    int r = tr * 2 + i;
    int tok = rT[r];
    if (tok >= 0) {
      float gv = rG[r];
      float* dst = acc + (size_t)tok * ND + tc * 8;
      const float* b2p = b2 + e * ND + tc * 8;
#pragma unroll
      for (int j = 0; j < 8; j++)
        atomicAdd(dst + j, gv * (y[i][j] + b2p[j]));
    }
  }
}

// ---------------------------------------------------------------------------
// moed_loss from importance
// ---------------------------------------------------------------------------
__global__ void k_loss(const float* __restrict__ imp, float* __restrict__ out) {
  if (threadIdx.x == 0 && blockIdx.x == 0) {
    float s = 0.f;
    for (int k = 0; k < 8; k++) s += imp[k];
    float mu = s * 0.125f;
    float v = 0.f;
    for (int k = 0; k < 8; k++) { float d = imp[k] - mu; v += d * d; }
    v *= (1.0f / 7.0f);
    out[8000000] = v / (mu * mu + 1e-10f);
  }
}

// ---------------------------------------------------------------------------
// added = mh + moe; instance-norm over G per (b,d); block = (b, 16-d chunk)
// ---------------------------------------------------------------------------
__global__ __launch_bounds__(256) void k_norm(const float* __restrict__ mh,
                                              const float* __restrict__ moe,
                                              const float* __restrict__ nw,
                                              const float* __restrict__ nb,
                                              float* __restrict__ outn) {
  int b = blockIdx.y;
  int d0 = blockIdx.x * 16;
  int tid = threadIdx.x;
  int dl = tid & 15, gs = tid >> 4;
  int d = d0 + dl;
  float s1 = 0.f, s2 = 0.f;
  for (int g = gs; g < NG; g += 16) {
    int idx = (b * NG + g) * ND + d;
    float x = mh[idx] + moe[idx];
    s1 += x; s2 += x * x;
  }
  __shared__ float r1[16][17], r2[16][17];
  __shared__ float sw[16], sb[16];
  r1[gs][dl] = s1; r2[gs][dl] = s2;
  __syncthreads();
  if (gs == 0) {
    float a = 0.f, q = 0.f;
    for (int k = 0; k < 16; k++) { a += r1[k][dl]; q += r2[k][dl]; }
    float mu = a * (1.0f / NG);
    float var = q * (1.0f / NG) - mu * mu;
    float rs = rsqrtf(var + 1e-5f);
    float w = nw[d] * rs;
    sw[dl] = w;
    sb[dl] = nb[d] - mu * w;
  }
  __syncthreads();
  float w = sw[dl], bb = sb[dl];
  for (int g = gs; g < NG; g += 16) {
    int idx = (b * NG + g) * ND + d;
    float x = mh[idx] + moe[idx];
    outn[idx] = x * w + bb;
  }
}

// ---------------------------------------------------------------------------
// final probs: score2 = normed @ enc^T, tanh-clip, +mask, softmax over p
// block = (b, 32-g tile); thread = (g_l, pc): 8 consecutive p per chunk
// ---------------------------------------------------------------------------
__global__ __launch_bounds__(256) void k_probs(const float* __restrict__ normed,
                                               const float* __restrict__ enc,
                                               const float* __restrict__ mask,
                                               float* __restrict__ out) {
  int b = blockIdx.y;
  int g0 = blockIdx.x * 32;
  int tid = threadIdx.x;
  int gl = tid >> 3, pc = tid & 7;
  int g = g0 + gl;
  __shared__ float nS[32][130];
  __shared__ float eT[128][68];
  for (int idx = tid; idx < 32 * 32; idx += 256) {
    int r = idx >> 5, dg = idx & 31;
    int gg = g0 + r;
    float4 v = (gg < NG) ? ((const float4*)normed)[(size_t)(b * NG + gg) * 32 + dg]
                         : make_float4(0.f, 0.f, 0.f, 0.f);
    nS[r][dg * 4 + 0] = v.x; nS[r][dg * 4 + 1] = v.y;
    nS[r][dg * 4 + 2] = v.z; nS[r][dg * 4 + 3] = v.w;
  }
  float sc[8][8];
#pragma unroll
  for (int ch = 0; ch < 8; ch++) {
    int p0 = ch * 64;
    __syncthreads();
    for (int idx = tid; idx < 64 * 32; idx += 256) {
      int pl = idx >> 5, dg = idx & 31;
      int pp = p0 + pl;
      float4 v = (pp < NP) ? ((const float4*)enc)[(size_t)(b * NP + pp) * 32 + dg]
                           : make_float4(0.f, 0.f, 0.f, 0.f);
      eT[dg * 4 + 0][pl] = v.x; eT[dg * 4 + 1][pl] = v.y;
      eT[dg * 4 + 2][pl] = v.z; eT[dg * 4 + 3][pl] = v.w;
    }
    __syncthreads();
    float a0 = 0, a1 = 0, a2 = 0, a3 = 0, a4 = 0, a5 = 0, a6 = 0, a7 = 0;
    for (int d = 0; d < 128; d++) {
      float nv = nS[gl][d];
      float4 e0 = *(const float4*)(&eT[d][pc * 8]);
      float4 e1 = *(const float4*)(&eT[d][pc * 8 + 4]);
      a0 += nv * e0.x; a1 += nv * e0.y; a2 += nv * e0.z; a3 += nv * e0.w;
      a4 += nv * e1.x; a5 += nv * e1.y; a6 += nv * e1.z; a7 += nv * e1.w;
    }
    sc[ch][0] = a0; sc[ch][1] = a1; sc[ch][2] = a2; sc[ch][3] = a3;
    sc[ch][4] = a4; sc[ch][5] = a5; sc[ch][6] = a6; sc[ch][7] = a7;
  }
  // tanh clip + mask, then softmax over the 500 p's of row g (8 lanes share g)
  const float* mrow = mask + (size_t)(b * NG + (g < NG ? g : NG - 1)) * NP;
  float m = -1e30f;
#pragma unroll
  for (int ch = 0; ch < 8; ch++) {
#pragma unroll
    for (int j = 0; j < 8; j++) {
      int p = ch * 64 + pc * 8 + j;
      float v;
      if (p < NP) {
        float x = sc[ch][j] * (1.0f / 11.313708498984761f);
        float e2 = __expf(2.0f * x);
        float th = (e2 - 1.0f) / (e2 + 1.0f);
        v = 10.0f * th + mrow[p];
      } else {
        v = -1e30f;
      }
      sc[ch][j] = v;
      m = fmaxf(m, v);
    }
  }
  m = fmaxf(m, __shfl_xor(m, 1));
  m = fmaxf(m, __shfl_xor(m, 2));
  m = fmaxf(m, __shfl_xor(m, 4));
  float sum = 0.f;
#pragma unroll
  for (int ch = 0; ch < 8; ch++) {
#pragma unroll
    for (int j = 0; j < 8; j++) {
      float e = __expf(sc[ch][j] - m);
      sc[ch][j] = e;
      sum += e;
    }
  }
  sum += __shfl_xor(sum, 1);
  sum += __shfl_xor(sum, 2);
  sum += __shfl_xor(sum, 4);
  float inv = 1.0f / sum;
  if (g < NG) {
    float* orow = out + (size_t)(b * NG + g) * NP;
#pragma unroll
    for (int ch = 0; ch < 8; ch++) {
      int p = ch * 64 + pc * 8;
#pragma unroll
      for (int j = 0; j < 8; j++)
        if (p + j < NP) orow[p + j] = sc[ch][j] * inv;
    }
  }
}

// ---------------------------------------------------------------------------
extern "C" void kernel_launch(void* const* d_in, const int* in_sizes, int n_in,
                              void* d_out, int out_size, void* d_ws, size_t ws_size,
                              hipStream_t stream) {
  const float* graph    = (const float*)d_in[0];
  const float* capacity = (const float*)d_in[1];
  const float* mask     = (const float*)d_in[2];
  const float* enc      = (const float*)d_in[3];
  const float* Wq       = (const float*)d_in[4];
  const float* Wk       = (const float*)d_in[5];
  const float* Wv       = (const float*)d_in[6];
  const float* Wc       = (const float*)d_in[7];
  const float* wg       = (const float*)d_in[8];
  const float* W1       = (const float*)d_in[9];
  const float* b1       = (const float*)d_in[10];
  const float* W2       = (const float*)d_in[11];
  const float* b2       = (const float*)d_in[12];
  const float* nw       = (const float*)d_in[13];
  const float* nb       = (const float*)d_in[14];
  float* out = (float*)d_out;
  float* ws = (float*)d_ws;

  float* kbuf = ws;                  // 2,048,000 f  (later reused as moe accum)
  float* vbuf = ws + 2048000;        // 2,048,000 f  (later reused as normed)
  float* att  = ws + 4096000;        // 2,048,000 f
  float* mh   = ws + 6144000;        // 2,048,000 f
  float* gq   = ws + 8192000;        // 4096 f
  int*   tlist = (int*)(ws + 8196096);   // 8*16000 int
  float* glist = ws + 8324096;           // 8*16000 f
  int*   cnt  = (int*)(ws + 8452096);    // 8 int
  float* imp  = ws + 8452104;            // 8 f

  k_kv<<<500, 256, 0, stream>>>(enc, Wk, Wv, kbuf, vbuf);
  k_graphq<<<32, 128, 0, stream>>>(graph, Wq, gq);
  k_attn<<<dim3(256, 2), 256, 0, stream>>>(kbuf, vbuf, capacity, gq, Wq, mask, att);
  // k/v consumed; reuse kbuf as MoE accumulator
  hipMemsetAsync(kbuf, 0, 2048000 * sizeof(float), stream);
  hipMemsetAsync(cnt, 0, 64, stream);  // cnt[8] + imp[8]
  k_comb<<<500, 256, 0, stream>>>(att, Wc, mh);
  k_gate<<<250, 256, 0, stream>>>(mh, wg, tlist, glist, cnt, imp);
  k_moe<<<dim3(500, 8), 256, 0, stream>>>(mh, W1, b1, W2, b2, tlist, glist, cnt, kbuf);
  k_loss<<<1, 64, 0, stream>>>(imp, out);
  k_norm<<<dim3(8, 32), 256, 0, stream>>>(mh, kbuf, nw, nb, vbuf);
  k_probs<<<dim3(16, 32), 256, 0, stream>>>(vbuf, enc, mask, out);
}

// Round 2
// 790.542 us; speedup vs baseline: 1.9771x; 1.9771x over previous
//
#include <hip/hip_runtime.h>
#include <math.h>

#define NB 32
#define NG 500
#define NP 500
#define ND 128
#define NH 8
#define NQK 16
#define NE 8
#define NFF 512
#define NT 16000   // B*G tokens

// ---------------------------------------------------------------------------
// K/V projection: C[16000 x 256] = enc @ [Wk | Wv], written to [B,H,P,16]
// block: 32 rows, 256 threads, thread tile 4 rows x 8 cols
// ---------------------------------------------------------------------------
__global__ __launch_bounds__(256) void k_kv(const float* __restrict__ enc,
                                            const float* __restrict__ Wk,
                                            const float* __restrict__ Wv,
                                            float* __restrict__ kbuf,
                                            float* __restrict__ vbuf) {
  int r0 = blockIdx.x * 32;
  int tid = threadIdx.x;
  __shared__ float encS[32][128];
  const float4* e4 = (const float4*)(enc + (size_t)r0 * 128);
  float4* s4 = (float4*)&encS[0][0];
#pragma unroll
  for (int i = 0; i < 4; i++) s4[tid + i * 256] = e4[tid + i * 256];
  __syncthreads();
  int cg = tid & 31, rg = tid >> 5;
  int c0 = cg * 8;  // col 0..255: [K cols | V cols]
  const float* W0 = (c0 < 128) ? (Wk + c0) : (Wv + (c0 - 128));
  float acc[4][8] = {};
  for (int d = 0; d < 128; d++) {
    float a0 = encS[rg * 4 + 0][d];
    float a1 = encS[rg * 4 + 1][d];
    float a2 = encS[rg * 4 + 2][d];
    float a3 = encS[rg * 4 + 3][d];
    float4 wlo = *(const float4*)(W0 + d * 128);
    float4 whi = *(const float4*)(W0 + d * 128 + 4);
    float w[8] = {wlo.x, wlo.y, wlo.z, wlo.w, whi.x, whi.y, whi.z, whi.w};
#pragma unroll
    for (int j = 0; j < 8; j++) {
      acc[0][j] += a0 * w[j];
      acc[1][j] += a1 * w[j];
      acc[2][j] += a2 * w[j];
      acc[3][j] += a3 * w[j];
    }
  }
#pragma unroll
  for (int i = 0; i < 4; i++) {
    int r = r0 + rg * 4 + i;
    int b = r / 500;
    int p = r - b * 500;
    int cc = (c0 < 128) ? c0 : (c0 - 128);
    int h = cc >> 4, qk = cc & 15;
    float* dst = (c0 < 128 ? kbuf : vbuf) + ((size_t)(b * 8 + h) * 500 + p) * 16 + qk;
    *(float4*)dst = make_float4(acc[i][0], acc[i][1], acc[i][2], acc[i][3]);
    *(float4*)(dst + 4) = make_float4(acc[i][4], acc[i][5], acc[i][6], acc[i][7]);
  }
}

// ---------------------------------------------------------------------------
// graphQ[b][j] = graph[b] @ Wq[0:128, j]
// ---------------------------------------------------------------------------
__global__ void k_graphq(const float* __restrict__ graph,
                         const float* __restrict__ Wq,
                         float* __restrict__ gq) {
  int b = blockIdx.x, j = threadIdx.x;
  float s = 0.f;
  for (int d = 0; d < 128; d++) s += graph[b * 128 + d] * Wq[d * 128 + j];
  gq[b * 128 + j] = s;
}

// ---------------------------------------------------------------------------
// attention: block = (b*8+h, half); 250 queries per block, online softmax
// ---------------------------------------------------------------------------
__global__ __launch_bounds__(256) void k_attn(const float* __restrict__ kbuf,
                                              const float* __restrict__ vbuf,
                                              const float* __restrict__ capacity,
                                              const float* __restrict__ gq,
                                              const float* __restrict__ Wq,
                                              const float* __restrict__ mask,
                                              float* __restrict__ att) {
  int bh = blockIdx.x;           // 0..255
  int half = blockIdx.y;         // 0..1
  int b = bh >> 3, h = bh & 7;
  int tid = threadIdx.x;
  __shared__ float ksh[NP][16];
  __shared__ float vsh[NP][16];
  const float4* kp = (const float4*)(kbuf + (size_t)bh * NP * 16);
  const float4* vp = (const float4*)(vbuf + (size_t)bh * NP * 16);
  float4* k4 = (float4*)&ksh[0][0];
  float4* v4 = (float4*)&vsh[0][0];
  for (int i = tid; i < NP * 4; i += 256) { k4[i] = kp[i]; v4[i] = vp[i]; }
  __syncthreads();
  if (tid < 250) {
    int g = half * 250 + tid;
    float cap = capacity[b * NG + g];
    float q[16];
#pragma unroll
    for (int j = 0; j < 16; j++)
      q[j] = gq[b * 128 + h * 16 + j] + cap * Wq[128 * 128 + h * 16 + j];
    float m = -1e30f, l = 0.f;
    float o[16] = {};
    const float* mrow = mask + ((size_t)(b * NG + g)) * NP;
    for (int p = 0; p < NP; p++) {
      const float4* kr = (const float4*)(&ksh[p][0]);
      float4 ka = kr[0], kb2 = kr[1], kc = kr[2], kd = kr[3];
      float s = q[0] * ka.x + q[1] * ka.y + q[2] * ka.z + q[3] * ka.w
              + q[4] * kb2.x + q[5] * kb2.y + q[6] * kb2.z + q[7] * kb2.w
              + q[8] * kc.x + q[9] * kc.y + q[10] * kc.z + q[11] * kc.w
              + q[12] * kd.x + q[13] * kd.y + q[14] * kd.z + q[15] * kd.w;
      s = s * 0.25f + mrow[p];
      if (s > m) {
        float c = __expf(m - s);
        l *= c;
#pragma unroll
        for (int j = 0; j < 16; j++) o[j] *= c;
        m = s;
      }
      float e = __expf(s - m);
      l += e;
      const float4* vr = (const float4*)(&vsh[p][0]);
      float4 va = vr[0], vb = vr[1], vc = vr[2], vd = vr[3];
      o[0] += e * va.x;  o[1] += e * va.y;  o[2] += e * va.z;  o[3] += e * va.w;
      o[4] += e * vb.x;  o[5] += e * vb.y;  o[6] += e * vb.z;  o[7] += e * vb.w;
      o[8] += e * vc.x;  o[9] += e * vc.y;  o[10] += e * vc.z; o[11] += e * vc.w;
      o[12] += e * vd.x; o[13] += e * vd.y; o[14] += e * vd.z; o[15] += e * vd.w;
    }
    float inv = 1.f / l;
    float* orow = att + ((size_t)(b * NG + g)) * 128 + h * 16;
#pragma unroll
    for (int j = 0; j < 16; j++) orow[j] = o[j] * inv;
  }
}

// ---------------------------------------------------------------------------
// mh = att(16000x128) @ Wcomb(128x128); block 32 rows, thread 2r x 8c
// ---------------------------------------------------------------------------
__global__ __launch_bounds__(256) void k_comb(const float* __restrict__ att,
                                              const float* __restrict__ Wc,
                                              float* __restrict__ mh) {
  int r0 = blockIdx.x * 32;
  int tid = threadIdx.x;
  __shared__ float aS[32][130];
  for (int idx = tid; idx < 32 * 32; idx += 256) {
    int r = idx >> 5, dg = idx & 31;
    float4 v = ((const float4*)att)[(size_t)(r0 + r) * 32 + dg];
    aS[r][dg * 4 + 0] = v.x; aS[r][dg * 4 + 1] = v.y;
    aS[r][dg * 4 + 2] = v.z; aS[r][dg * 4 + 3] = v.w;
  }
  __syncthreads();
  int cg = tid & 15, rg = tid >> 4;
  float acc[2][8] = {};
  for (int d = 0; d < 128; d++) {
    float a0 = aS[rg * 2 + 0][d];
    float a1 = aS[rg * 2 + 1][d];
    float4 wlo = *(const float4*)(Wc + d * 128 + cg * 8);
    float4 whi = *(const float4*)(Wc + d * 128 + cg * 8 + 4);
    float w[8] = {wlo.x, wlo.y, wlo.z, wlo.w, whi.x, whi.y, whi.z, whi.w};
#pragma unroll
    for (int j = 0; j < 8; j++) {
      acc[0][j] += a0 * w[j];
      acc[1][j] += a1 * w[j];
    }
  }
#pragma unroll
  for (int i = 0; i < 2; i++) {
    float* dst = mh + (size_t)(r0 + rg * 2 + i) * 128 + cg * 8;
    *(float4*)dst = make_float4(acc[i][0], acc[i][1], acc[i][2], acc[i][3]);
    *(float4*)(dst + 4) = make_float4(acc[i][4], acc[i][5], acc[i][6], acc[i][7]);
  }
}

// ---------------------------------------------------------------------------
// gating: logits, top-2, softmax gates; hierarchical bucketing
// block = 256 tokens; LDS atomics for rank, 8 global atomics/block for base
// ---------------------------------------------------------------------------
__global__ __launch_bounds__(256) void k_gate(const float* __restrict__ mh,
                                              const float* __restrict__ wg,
                                              int* __restrict__ tlist,
                                              float* __restrict__ glist,
                                              int* __restrict__ cnt,
                                              float* __restrict__ imp) {
  int t0 = blockIdx.x * 256;
  int tid = threadIdx.x;
  __shared__ float wgS[128 * 8];
  __shared__ int lcnt[8];
  __shared__ float limp[8];
  __shared__ int lbase[8];
  for (int i = tid; i < 1024; i += 256) wgS[i] = wg[i];
  if (tid < 8) { lcnt[tid] = 0; limp[tid] = 0.f; }
  __syncthreads();
  int t = t0 + tid;
  bool ok = (t < NT);
  int i0 = 0, i1 = 0, r0 = 0, r1 = 0;
  float g0 = 0.f, g1 = 0.f;
  if (ok) {
    float lg[8] = {};
    const float* row = mh + (size_t)t * ND;
    for (int d = 0; d < ND; d += 4) {
      float4 x4 = *(const float4*)(row + d);
      float xs[4] = {x4.x, x4.y, x4.z, x4.w};
#pragma unroll
      for (int u = 0; u < 4; u++)
#pragma unroll
        for (int k = 0; k < 8; k++) lg[k] += xs[u] * wgS[(d + u) * 8 + k];
    }
    float v0 = -1e30f, v1 = -1e30f;
#pragma unroll
    for (int k = 0; k < 8; k++) {
      float l = lg[k];
      if (l > v0) { v1 = v0; i1 = i0; v0 = l; i0 = k; }
      else if (l > v1) { v1 = l; i1 = k; }
    }
    float ex = __expf(v1 - v0);
    float den = 1.0f + ex;
    g0 = 1.0f / den; g1 = ex / den;
    atomicAdd(&limp[i0], g0);
    atomicAdd(&limp[i1], g1);
    r0 = atomicAdd(&lcnt[i0], 1);
    r1 = atomicAdd(&lcnt[i1], 1);
  }
  __syncthreads();
  if (tid < 8) {
    lbase[tid] = atomicAdd(&cnt[tid], lcnt[tid]);
    atomicAdd(&imp[tid], limp[tid]);
  }
  __syncthreads();
  if (ok) {
    int p0 = lbase[i0] + r0;
    tlist[i0 * NT + p0] = t; glist[i0 * NT + p0] = g0;
    int p1 = lbase[i1] + r1;
    tlist[i1 * NT + p1] = t; glist[i1 * NT + p1] = g1;
  }
}

// ---------------------------------------------------------------------------
// MoE expert FFN: block = (token-tile 32, expert); two-stage GEMM via LDS h
// ---------------------------------------------------------------------------
__global__ __launch_bounds__(256) void k_moe(const float* __restrict__ mh,
                                             const float* __restrict__ W1,
                                             const float* __restrict__ b1,
                                             const float* __restrict__ W2,
                                             const float* __restrict__ b2,
                                             const int* __restrict__ tlist,
                                             const float* __restrict__ glist,
                                             const int* __restrict__ cnt,
                                             float* __restrict__ acc) {
  int e = blockIdx.y;
  int n = cnt[e];
  int t0 = blockIdx.x * 32;
  if (t0 >= n) return;
  int tid = threadIdx.x;
  __shared__ float tS[32][129];
  __shared__ float hS[32][65];
  __shared__ int rT[32];
  __shared__ float rG[32];
  if (tid < 32) {
    int ok = (t0 + tid) < n;
    rT[tid] = ok ? tlist[e * NT + t0 + tid] : -1;
    rG[tid] = ok ? glist[e * NT + t0 + tid] : 0.f;
  }
  __syncthreads();
  for (int idx = tid; idx < 32 * 32; idx += 256) {
    int r = idx >> 5, dg = idx & 31;
    int tok = rT[r];
    float4 v = (tok >= 0) ? ((const float4*)mh)[(size_t)tok * 32 + dg]
                          : make_float4(0.f, 0.f, 0.f, 0.f);
    tS[r][dg * 4 + 0] = v.x; tS[r][dg * 4 + 1] = v.y;
    tS[r][dg * 4 + 2] = v.z; tS[r][dg * 4 + 3] = v.w;
  }
  __syncthreads();
  int tc = tid & 15, tr = tid >> 4;
  float y[2][8] = {};
  for (int fc = 0; fc < NFF; fc += 64) {
    // phase A: h chunk [32 tok][64 f], thread = 2 rows x 4 f
    float h00 = 0, h01 = 0, h02 = 0, h03 = 0, h10 = 0, h11 = 0, h12 = 0, h13 = 0;
    const float* w1p = W1 + (size_t)e * ND * NFF + fc + tc * 4;
    for (int d = 0; d < ND; d++) {
      float a0 = tS[tr * 2 + 0][d];
      float a1 = tS[tr * 2 + 1][d];
      float4 w = *(const float4*)(w1p + (size_t)d * NFF);
      h00 += a0 * w.x; h01 += a0 * w.y; h02 += a0 * w.z; h03 += a0 * w.w;
      h10 += a1 * w.x; h11 += a1 * w.y; h12 += a1 * w.z; h13 += a1 * w.w;
    }
    float4 bb = *(const float4*)(b1 + e * NFF + fc + tc * 4);
    hS[tr * 2 + 0][tc * 4 + 0] = fmaxf(h00 + bb.x, 0.f);
    hS[tr * 2 + 0][tc * 4 + 1] = fmaxf(h01 + bb.y, 0.f);
    hS[tr * 2 + 0][tc * 4 + 2] = fmaxf(h02 + bb.z, 0.f);
    hS[tr * 2 + 0][tc * 4 + 3] = fmaxf(h03 + bb.w, 0.f);
    hS[tr * 2 + 1][tc * 4 + 0] = fmaxf(h10 + bb.x, 0.f);
    hS[tr * 2 + 1][tc * 4 + 1] = fmaxf(h11 + bb.y, 0.f);
    hS[tr * 2 + 1][tc * 4 + 2] = fmaxf(h12 + bb.z, 0.f);
    hS[tr * 2 + 1][tc * 4 + 3] = fmaxf(h13 + bb.w, 0.f);
    __syncthreads();
    // phase B: y += relu(h) @ W2chunk, thread = 2 rows x 8 cols
    const float* w2p = W2 + ((size_t)e * NFF + fc) * ND + tc * 8;
    for (int f = 0; f < 64; f++) {
      float p0 = hS[tr * 2 + 0][f];
      float p1 = hS[tr * 2 + 1][f];
      float4 wa = *(const float4*)(w2p + (size_t)f * ND);
      float4 wb = *(const float4*)(w2p + (size_t)f * ND + 4);
      y[0][0] += p0 * wa.x; y[0][1] += p0 * wa.y; y[0][2] += p0 * wa.z; y[0][3] += p0 * wa.w;
      y[0][4] += p0 * wb.x; y[0][5] += p0 * wb.y; y[0][6] += p0 * wb.z; y[0][7] += p0 * wb.w;
      y[1][0] += p1 * wa.x; y[1][1] += p1 * wa.y; y[1][2] += p1 * wa.z; y[1][3] += p1 * wa.w;
      y[1][4] += p1 * wb.x; y[1][5] += p1 * wb.y; y[1][6] += p1 * wb.z; y[1][7] += p1 * wb.w;
    }
    __syncthreads();
  }
#pragma unroll
  for (int i = 0; i < 2; i++) {
    int r = tr * 2 + i;
    int tok = rT[r];
    if (tok >= 0) {
      float gv = rG[r];
      float* dst = acc + (size_t)tok * ND + tc * 8;
      const float* b2p = b2 + e * ND + tc * 8;
#pragma unroll
      for (int j = 0; j < 8; j++)
        atomicAdd(dst + j, gv * (y[i][j] + b2p[j]));
    }
  }
}

// ---------------------------------------------------------------------------
// moed_loss from importance
// ---------------------------------------------------------------------------
__global__ void k_loss(const float* __restrict__ imp, float* __restrict__ out) {
  if (threadIdx.x == 0 && blockIdx.x == 0) {
    float s = 0.f;
    for (int k = 0; k < 8; k++) s += imp[k];
    float mu = s * 0.125f;
    float v = 0.f;
    for (int k = 0; k < 8; k++) { float d = imp[k] - mu; v += d * d; }
    v *= (1.0f / 7.0f);
    out[8000000] = v / (mu * mu + 1e-10f);
  }
}

// ---------------------------------------------------------------------------
// added = mh + moe; instance-norm over G per (b,d); block = (b, 16-d chunk)
// ---------------------------------------------------------------------------
__global__ __launch_bounds__(256) void k_norm(const float* __restrict__ mh,
                                              const float* __restrict__ moe,
                                              const float* __restrict__ nw,
                                              const float* __restrict__ nb,
                                              float* __restrict__ outn) {
  int b = blockIdx.y;
  int d0 = blockIdx.x * 16;
  int tid = threadIdx.x;
  int dl = tid & 15, gs = tid >> 4;
  int d = d0 + dl;
  float s1 = 0.f, s2 = 0.f;
  for (int g = gs; g < NG; g += 16) {
    int idx = (b * NG + g) * ND + d;
    float x = mh[idx] + moe[idx];
    s1 += x; s2 += x * x;
  }
  __shared__ float r1[16][17], r2[16][17];
  __shared__ float sw[16], sb[16];
  r1[gs][dl] = s1; r2[gs][dl] = s2;
  __syncthreads();
  if (gs == 0) {
    float a = 0.f, q = 0.f;
    for (int k = 0; k < 16; k++) { a += r1[k][dl]; q += r2[k][dl]; }
    float mu = a * (1.0f / NG);
    float var = q * (1.0f / NG) - mu * mu;
    float rs = rsqrtf(var + 1e-5f);
    float w = nw[d] * rs;
    sw[dl] = w;
    sb[dl] = nb[d] - mu * w;
  }
  __syncthreads();
  float w = sw[dl], bb = sb[dl];
  for (int g = gs; g < NG; g += 16) {
    int idx = (b * NG + g) * ND + d;
    float x = mh[idx] + moe[idx];
    outn[idx] = x * w + bb;
  }
}

// ---------------------------------------------------------------------------
// final probs: score2 = normed @ enc^T, tanh-clip, +mask, softmax over p
// block = (b, 32-g tile); thread = (g_l, pc): 8 consecutive p per chunk
// ---------------------------------------------------------------------------
__global__ __launch_bounds__(256) void k_probs(const float* __restrict__ normed,
                                               const float* __restrict__ enc,
                                               const float* __restrict__ mask,
                                               float* __restrict__ out) {
  int b = blockIdx.y;
  int g0 = blockIdx.x * 32;
  int tid = threadIdx.x;
  int gl = tid >> 3, pc = tid & 7;
  int g = g0 + gl;
  __shared__ float nS[32][130];
  __shared__ float eT[128][68];
  for (int idx = tid; idx < 32 * 32; idx += 256) {
    int r = idx >> 5, dg = idx & 31;
    int gg = g0 + r;
    float4 v = (gg < NG) ? ((const float4*)normed)[(size_t)(b * NG + gg) * 32 + dg]
                         : make_float4(0.f, 0.f, 0.f, 0.f);
    nS[r][dg * 4 + 0] = v.x; nS[r][dg * 4 + 1] = v.y;
    nS[r][dg * 4 + 2] = v.z; nS[r][dg * 4 + 3] = v.w;
  }
  float sc[8][8];
#pragma unroll
  for (int ch = 0; ch < 8; ch++) {
    int p0 = ch * 64;
    __syncthreads();
    for (int idx = tid; idx < 64 * 32; idx += 256) {
      int pl = idx >> 5, dg = idx & 31;
      int pp = p0 + pl;
      float4 v = (pp < NP) ? ((const float4*)enc)[(size_t)(b * NP + pp) * 32 + dg]
                           : make_float4(0.f, 0.f, 0.f, 0.f);
      eT[dg * 4 + 0][pl] = v.x; eT[dg * 4 + 1][pl] = v.y;
      eT[dg * 4 + 2][pl] = v.z; eT[dg * 4 + 3][pl] = v.w;
    }
    __syncthreads();
    float a0 = 0, a1 = 0, a2 = 0, a3 = 0, a4 = 0, a5 = 0, a6 = 0, a7 = 0;
    for (int d = 0; d < 128; d++) {
      float nv = nS[gl][d];
      float4 e0 = *(const float4*)(&eT[d][pc * 8]);
      float4 e1 = *(const float4*)(&eT[d][pc * 8 + 4]);
      a0 += nv * e0.x; a1 += nv * e0.y; a2 += nv * e0.z; a3 += nv * e0.w;
      a4 += nv * e1.x; a5 += nv * e1.y; a6 += nv * e1.z; a7 += nv * e1.w;
    }
    sc[ch][0] = a0; sc[ch][1] = a1; sc[ch][2] = a2; sc[ch][3] = a3;
    sc[ch][4] = a4; sc[ch][5] = a5; sc[ch][6] = a6; sc[ch][7] = a7;
  }
  // tanh clip + mask, then softmax over the 500 p's of row g (8 lanes share g)
  const float* mrow = mask + (size_t)(b * NG + (g < NG ? g : NG - 1)) * NP;
  float m = -1e30f;
#pragma unroll
  for (int ch = 0; ch < 8; ch++) {
#pragma unroll
    for (int j = 0; j < 8; j++) {
      int p = ch * 64 + pc * 8 + j;
      float v;
      if (p < NP) {
        float x = sc[ch][j] * (1.0f / 11.313708498984761f);
        float e2 = __expf(2.0f * x);
        float th = (e2 - 1.0f) / (e2 + 1.0f);
        v = 10.0f * th + mrow[p];
      } else {
        v = -1e30f;
      }
      sc[ch][j] = v;
      m = fmaxf(m, v);
    }
  }
  m = fmaxf(m, __shfl_xor(m, 1));
  m = fmaxf(m, __shfl_xor(m, 2));
  m = fmaxf(m, __shfl_xor(m, 4));
  float sum = 0.f;
#pragma unroll
  for (int ch = 0; ch < 8; ch++) {
#pragma unroll
    for (int j = 0; j < 8; j++) {
      float e = __expf(sc[ch][j] - m);
      sc[ch][j] = e;
      sum += e;
    }
  }
  sum += __shfl_xor(sum, 1);
  sum += __shfl_xor(sum, 2);
  sum += __shfl_xor(sum, 4);
  float inv = 1.0f / sum;
  if (g < NG) {
    float* orow = out + (size_t)(b * NG + g) * NP;
#pragma unroll
    for (int ch = 0; ch < 8; ch++) {
      int p = ch * 64 + pc * 8;
#pragma unroll
      for (int j = 0; j < 8; j++)
        if (p + j < NP) orow[p + j] = sc[ch][j] * inv;
    }
  }
}

// ---------------------------------------------------------------------------
extern "C" void kernel_launch(void* const* d_in, const int* in_sizes, int n_in,
                              void* d_out, int out_size, void* d_ws, size_t ws_size,
                              hipStream_t stream) {
  const float* graph    = (const float*)d_in[0];
  const float* capacity = (const float*)d_in[1];
  const float* mask     = (const float*)d_in[2];
  const float* enc      = (const float*)d_in[3];
  const float* Wq       = (const float*)d_in[4];
  const float* Wk       = (const float*)d_in[5];
  const float* Wv       = (const float*)d_in[6];
  const float* Wc       = (const float*)d_in[7];
  const float* wg       = (const float*)d_in[8];
  const float* W1       = (const float*)d_in[9];
  const float* b1       = (const float*)d_in[10];
  const float* W2       = (const float*)d_in[11];
  const float* b2       = (const float*)d_in[12];
  const float* nw       = (const float*)d_in[13];
  const float* nb       = (const float*)d_in[14];
  float* out = (float*)d_out;
  float* ws = (float*)d_ws;

  float* kbuf = ws;                  // 2,048,000 f  (later reused as moe accum)
  float* vbuf = ws + 2048000;        // 2,048,000 f  (later reused as normed)
  float* att  = ws + 4096000;        // 2,048,000 f
  float* mh   = ws + 6144000;        // 2,048,000 f
  float* gq   = ws + 8192000;        // 4096 f
  int*   tlist = (int*)(ws + 8196096);   // 8*16000 int
  float* glist = ws + 8324096;           // 8*16000 f
  int*   cnt  = (int*)(ws + 8452096);    // 8 int
  float* imp  = ws + 8452104;            // 8 f

  k_kv<<<500, 256, 0, stream>>>(enc, Wk, Wv, kbuf, vbuf);
  k_graphq<<<32, 128, 0, stream>>>(graph, Wq, gq);
  k_attn<<<dim3(256, 2), 256, 0, stream>>>(kbuf, vbuf, capacity, gq, Wq, mask, att);
  // k/v consumed; reuse kbuf as MoE accumulator
  hipMemsetAsync(kbuf, 0, 2048000 * sizeof(float), stream);
  hipMemsetAsync(cnt, 0, 64, stream);  // cnt[8] + imp[8]
  k_comb<<<500, 256, 0, stream>>>(att, Wc, mh);
  k_gate<<<63, 256, 0, stream>>>(mh, wg, tlist, glist, cnt, imp);
  k_moe<<<dim3(500, 8), 256, 0, stream>>>(mh, W1, b1, W2, b2, tlist, glist, cnt, kbuf);
  k_loss<<<1, 64, 0, stream>>>(imp, out);
  k_norm<<<dim3(8, 32), 256, 0, stream>>>(mh, kbuf, nw, nb, vbuf);
  k_probs<<<dim3(16, 32), 256, 0, stream>>>(vbuf, enc, mask, out);
}